// Round 3
// baseline (331.159 us; speedup 1.0000x reference)
//
#include <hip/hip_runtime.h>
#include <hip/hip_bf16.h>
#include <stdint.h>

typedef __bf16 bf16;
typedef __bf16 v8bf __attribute__((ext_vector_type(8)));
typedef float  v4f  __attribute__((ext_vector_type(4)));

#define TSEQ   2048
#define HIDDIM 2048
#define NHEAD  16
#define HDIM   128
#define CPS    6   // key-chunks (of 64) per attn split-block

// async global->LDS, 16B per lane, LDS dest = wave-uniform base + lane*16 (m97 pattern)
__device__ __forceinline__ void async16(void* lds, const void* g)
{
    __builtin_amdgcn_global_load_lds(
        (__attribute__((address_space(1))) void*)(uintptr_t)g,
        (__attribute__((address_space(3))) void*)(unsigned int)(uintptr_t)lds,
        16, 0, 0);
}

// ---------------- f32 -> bf16 bulk convert: 5 matrices of TSEQ*HIDDIM ----------------
__global__ __launch_bounds__(256) void conv5(const float* __restrict__ s0, bf16* __restrict__ d0,
                                             const float* __restrict__ s1, bf16* __restrict__ d1,
                                             const float* __restrict__ s2, bf16* __restrict__ d2,
                                             const float* __restrict__ s3, bf16* __restrict__ d3,
                                             const float* __restrict__ s4, bf16* __restrict__ d4)
{
    const float* src; bf16* dst;
    switch (blockIdx.y) {
        case 0: src = s0; dst = d0; break;
        case 1: src = s1; dst = d1; break;
        case 2: src = s2; dst = d2; break;
        case 3: src = s3; dst = d3; break;
        default: src = s4; dst = d4; break;
    }
    const size_t i = ((size_t)blockIdx.x * 256 + threadIdx.x) * 8;
    const float4 a = *(const float4*)(src + i);
    const float4 b = *(const float4*)(src + i + 4);
    v8bf o;
    o[0] = (bf16)a.x; o[1] = (bf16)a.y; o[2] = (bf16)a.z; o[3] = (bf16)a.w;
    o[4] = (bf16)b.x; o[5] = (bf16)b.y; o[6] = (bf16)b.z; o[7] = (bf16)b.w;
    *(v8bf*)(dst + i) = o;
}

// ------- NT GEMM body: C[M,N](+)= A[M,K[k0:k1]] * B[N,K[k0:k1]]^T, 128x128 tile, BK=32 -------
template <typename CT, bool ATOMIC>
__device__ __forceinline__ void gemm_body(const bf16* __restrict__ A,
                                          const bf16* __restrict__ B,
                                          CT* __restrict__ C,
                                          int m0, int n0, int k0, int k1, int K, int ldc)
{
    __shared__ __attribute__((aligned(16))) bf16 sA[128*32];
    __shared__ __attribute__((aligned(16))) bf16 sB[128*32];
    const int tid  = threadIdx.x;
    const int lane = tid & 63;
    const int w    = tid >> 6;           // wave 0..3
    const int wm   = w >> 1, wn = w & 1; // 2x2 waves of 64x64
    const int quad = lane >> 4, lr = lane & 15;
    const int srow = lane >> 2;          // staging: 16 rows x 4 lanes/row
    const int scol = (lane & 3) * 8;

    const bf16* gA0 = A + (size_t)(m0 + w*32 + srow) * K + scol;
    const bf16* gB0 = B + (size_t)(n0 + w*32 + srow) * K + scol;
    bf16* lA0 = &sA[w*1024];
    bf16* lB0 = &sB[w*1024];

    v4f acc[4][4] = {};

    for (int kt = k0; kt < k1; kt += 32) {
        __syncthreads();                         // prev-iter LDS reads done
        async16(lA0,       gA0 + kt);
        async16(lA0 + 512, gA0 + (size_t)16*K + kt);
        async16(lB0,       gB0 + kt);
        async16(lB0 + 512, gB0 + (size_t)16*K + kt);
        __syncthreads();                         // drains vmcnt -> tiles visible
        v8bf a[4], b[4];
#pragma unroll
        for (int i = 0; i < 4; ++i)
            a[i] = *(const v8bf*)&sA[(wm*64 + i*16 + lr)*32 + quad*8];
#pragma unroll
        for (int j = 0; j < 4; ++j)
            b[j] = *(const v8bf*)&sB[(wn*64 + j*16 + lr)*32 + quad*8];
#pragma unroll
        for (int i = 0; i < 4; ++i)
#pragma unroll
            for (int j = 0; j < 4; ++j)
                acc[i][j] = __builtin_amdgcn_mfma_f32_16x16x32_bf16(a[i], b[j], acc[i][j], 0, 0, 0);
    }

#pragma unroll
    for (int i = 0; i < 4; ++i) {
        const int row_b = m0 + wm*64 + i*16 + quad*4;
#pragma unroll
        for (int j = 0; j < 4; ++j) {
            const int col = n0 + wn*64 + j*16 + lr;
#pragma unroll
            for (int r = 0; r < 4; ++r) {
                if constexpr (ATOMIC)
                    atomicAdd(&C[(size_t)(row_b + r)*ldc + col], acc[i][j][r]);
                else
                    C[(size_t)(row_b + r)*ldc + col] = (CT)acc[i][j][r];
            }
        }
    }
}

__global__ __launch_bounds__(256) void gemm_qkv(const bf16* __restrict__ A,
    const bf16* __restrict__ Wq, const bf16* __restrict__ Wk, const bf16* __restrict__ Wv,
    bf16* __restrict__ qb, bf16* __restrict__ kb, bf16* __restrict__ vb)
{
    const int which = blockIdx.x >> 4;                   // 0:q 1:k 2:v
    const int n0 = (blockIdx.x & 15) * 128;
    const int m0 = blockIdx.y * 128;
    const bf16* B = (which == 0) ? Wq : (which == 1) ? Wk : Wv;
    bf16* C = (which == 0) ? qb : (which == 1) ? kb : vb;
    gemm_body<bf16, false>(A, B, C, m0, n0, 0, HIDDIM, HIDDIM, HIDDIM);
}

// split-K=2 output GEMM: fp32 atomic accumulate into zeroed C
__global__ __launch_bounds__(256) void gemm_out_sk(const bf16* __restrict__ A,
    const bf16* __restrict__ B, float* __restrict__ C)
{
    const int k0 = blockIdx.z * (HIDDIM/2);
    gemm_body<float, true>(A, B, C, blockIdx.y*128, blockIdx.x*128,
                           k0, k0 + HIDDIM/2, HIDDIM, HIDDIM);
}

// ---------------- ReBased feature map: y = LN(x*gamma+beta), q also * D^-0.5 ----------------
__global__ __launch_bounds__(256) void fmap(bf16* __restrict__ qb, bf16* __restrict__ kb,
                                            const float* __restrict__ gamma,
                                            const float* __restrict__ beta)
{
    const int rid  = blockIdx.x * 4 + (threadIdx.x >> 6);   // 0 .. 2*T*H-1
    const int lane = threadIdx.x & 63;
    bf16* base = (rid < TSEQ*NHEAD) ? (qb + (size_t)rid * HDIM)
                                    : (kb + (size_t)(rid - TSEQ*NHEAD) * HDIM);
    const float scale = (rid < TSEQ*NHEAD) ? 0.08838834764831845f : 1.0f; // D^-0.5 on q only

    const bf16 x0b = base[lane*2], x1b = base[lane*2+1];
    const float g0 = gamma[lane*2], g1 = gamma[lane*2+1];
    const float b0 = beta[lane*2],  b1 = beta[lane*2+1];
    float x0 = (float)x0b*g0 + b0;
    float x1 = (float)x1b*g1 + b1;
    float s  = x0 + x1;
    float sq = x0*x0 + x1*x1;
#pragma unroll
    for (int off = 1; off < 64; off <<= 1) { s += __shfl_xor(s, off); sq += __shfl_xor(sq, off); }
    const float mu   = s * (1.0f/128.0f);
    float var        = sq * (1.0f/128.0f) - mu*mu;
    var = fmaxf(var, 0.0f);
    const float rstd = rsqrtf(var + 1e-5f);
    base[lane*2]   = (bf16)((x0 - mu) * rstd * scale);
    base[lane*2+1] = (bf16)((x1 - mu) * rstd * scale);
}

// ---------------- 2048x2048 transpose (vt[c][t] = vb[t][c]) ----------------
__global__ __launch_bounds__(256) void transpose2048(const bf16* __restrict__ src,
                                                     bf16* __restrict__ dst)
{
    __shared__ __attribute__((aligned(16))) bf16 tile[64][72];
    const int t0 = blockIdx.y * 64, c0 = blockIdx.x * 64;
    const int tid = threadIdx.x;
    const int r = tid >> 3;            // 0..31
    const int c = (tid & 7) * 8;       // 0..56
#pragma unroll
    for (int p = 0; p < 2; ++p) {
        const int rr = r + p*32;
        *(v8bf*)&tile[rr][c] = *(const v8bf*)(src + (size_t)(t0+rr)*HIDDIM + c0 + c);
    }
    __syncthreads();
#pragma unroll
    for (int p = 0; p < 2; ++p) {
        const int orow = r + p*32;     // output row = original column
        v8bf o;
#pragma unroll
        for (int i = 0; i < 8; ++i) o[i] = tile[c + i][orow];
        *(v8bf*)(dst + (size_t)(c0+orow)*HIDDIM + t0 + c) = o;
    }
}

// ---------------- quadratic causal attention, split over key chunks ----------------
// grid (51 splits, 16 heads). Each block: one (head, 128-row q-tile) x <=CPS key-chunks.
// Partial O -> fp32 atomicAdd into O_ws (=d_out, zeroed); partial z -> z_ws.
__global__ __launch_bounds__(256, 2) void attn(const bf16* __restrict__ qb,
                                               const bf16* __restrict__ kb,
                                               const bf16* __restrict__ vt,
                                               float* __restrict__ O_ws,
                                               float* __restrict__ z_ws)
{
    __shared__ __attribute__((aligned(16))) bf16 sK[64*136];   // [s][d], pad 8
    __shared__ __attribute__((aligned(16))) bf16 sV[128*72];   // [d][s], pad 8
    __shared__ __attribute__((aligned(16))) bf16 sS[128*72];   // [q][s], pad 8
    // map blockIdx.x -> (qt, chunk range), big qt first
    int bx = blockIdx.x;
    int qt = 15, c0 = 0;
#pragma unroll
    for (int qq = 15; qq >= 0; --qq) {
        const int ns = (2*qq + 7) / CPS;          // ceil((2qq+2)/6)
        if (bx < ns) { qt = qq; c0 = bx * CPS; break; }
        bx -= ns;
    }
    const int nch = 2*qt + 2;
    const int c1  = min(nch, c0 + CPS);

    const int h   = blockIdx.y;
    const int tid = threadIdx.x, lane = tid & 63, w = tid >> 6;
    const int quad = lane >> 4, lr = lane & 15;

    // Q fragments (A-layout), held in registers for the whole block
    v8bf qa[2][4];
    {
        const bf16* q0 = qb + (size_t)(qt*128 + w*32 + lr)*HIDDIM + h*HDIM + quad*8;
#pragma unroll
        for (int mi = 0; mi < 2; ++mi)
#pragma unroll
            for (int ks = 0; ks < 4; ++ks)
                qa[mi][ks] = *(const v8bf*)(q0 + (size_t)mi*16*HIDDIM + ks*32);
    }

    v4f  o[2][8] = {};
    float z[2][4] = {};

    for (int ch = c0; ch < c1; ++ch) {
        const int s0 = ch * 64;
        const bool diag = (s0 + 63 > qt*128);
        __syncthreads();                        // prev-chunk LDS reads done
        {   // stage K tile [64 s][128 d]
            const int r  = tid >> 4;            // 0..15
            const int c  = (tid & 15) * 8;
#pragma unroll
            for (int p = 0; p < 4; ++p) {
                const int rr = r + p*16;
                *(v8bf*)&sK[rr*136 + c] =
                    *(const v8bf*)(kb + (size_t)(s0+rr)*HIDDIM + h*HDIM + c);
            }
            // stage Vt tile [128 d][64 s]
            const int r2 = tid >> 3;            // 0..31
            const int c2 = (tid & 7) * 8;
#pragma unroll
            for (int p = 0; p < 4; ++p) {
                const int rr = r2 + p*32;
                *(v8bf*)&sV[rr*72 + c2] =
                    *(const v8bf*)(vt + (size_t)(h*HDIM+rr)*HIDDIM + s0 + c2);
            }
        }
        __syncthreads();                        // tiles visible

        // QK^T -> square/mask -> z, sS (sS rows are wave-private: no barrier needed)
        v8bf kbf[4][4];
#pragma unroll
        for (int nj = 0; nj < 4; ++nj)
#pragma unroll
            for (int ks = 0; ks < 4; ++ks)
                kbf[nj][ks] = *(const v8bf*)&sK[(nj*16 + lr)*136 + ks*32 + quad*8];
#pragma unroll
        for (int mi = 0; mi < 2; ++mi) {
#pragma unroll
            for (int nj = 0; nj < 4; ++nj) {
                v4f s4 = {0.f, 0.f, 0.f, 0.f};
#pragma unroll
                for (int ks = 0; ks < 4; ++ks)
                    s4 = __builtin_amdgcn_mfma_f32_16x16x32_bf16(qa[mi][ks], kbf[nj][ks], s4, 0, 0, 0);
                const int row_l = w*32 + mi*16 + quad*4;
                const int col   = nj*16 + lr;
                const int qg    = qt*128 + row_l;
                const int sg    = s0 + col;
#pragma unroll
                for (int r = 0; r < 4; ++r) {
                    float val = s4[r] * s4[r];
                    if (diag && (sg > qg + r)) val = 0.0f;
                    const bf16 vb16 = (bf16)val;
                    z[mi][r] += (float)vb16;    // consistent with what multiplies V
                    sS[(row_l + r)*72 + col] = vb16;
                }
            }
        }

        // O += S * V
#pragma unroll
        for (int ks = 0; ks < 2; ++ks) {
            v8bf sa[2];
#pragma unroll
            for (int mi = 0; mi < 2; ++mi)
                sa[mi] = *(const v8bf*)&sS[(w*32 + mi*16 + lr)*72 + ks*32 + quad*8];
#pragma unroll
            for (int nd = 0; nd < 8; ++nd) {
                const v8bf vb = *(const v8bf*)&sV[(nd*16 + lr)*72 + ks*32 + quad*8];
#pragma unroll
                for (int mi = 0; mi < 2; ++mi)
                    o[mi][nd] = __builtin_amdgcn_mfma_f32_16x16x32_bf16(sa[mi], vb, o[mi][nd], 0, 0, 0);
            }
        }
    }

    // partial z: reduce across the 16-lane group, one atomic per row per wave
#pragma unroll
    for (int mi = 0; mi < 2; ++mi) {
        const int row_l = w*32 + mi*16 + quad*4;
#pragma unroll
        for (int r = 0; r < 4; ++r) {
            float zz = z[mi][r];
            zz += __shfl_xor(zz, 1); zz += __shfl_xor(zz, 2);
            zz += __shfl_xor(zz, 4); zz += __shfl_xor(zz, 8);
            if (lr == 0)
                atomicAdd(&z_ws[h*TSEQ + qt*128 + row_l + r], zz);
        }
    }

    // partial O: fp32 atomic accumulate
#pragma unroll
    for (int mi = 0; mi < 2; ++mi) {
        const int row_l = w*32 + mi*16 + quad*4;
        const size_t rbase = (size_t)(qt*128 + row_l)*HIDDIM + h*HDIM;
#pragma unroll
        for (int nd = 0; nd < 8; ++nd) {
            const int col = nd*16 + lr;
#pragma unroll
            for (int r = 0; r < 4; ++r)
                atomicAdd(&O_ws[rbase + (size_t)r*HIDDIM + col], o[mi][nd][r]);
        }
    }
}

// ---------------- ob[t][h*128+d] = bf16( O[t][h*128+d] / (z[h][t]+eps) ) ----------------
__global__ __launch_bounds__(256) void norm_div(const float* __restrict__ O_ws,
                                                const float* __restrict__ z_ws,
                                                bf16* __restrict__ ob)
{
    const size_t i = ((size_t)blockIdx.x * 256 + threadIdx.x) * 8;
    const int t = (int)(i >> 11);
    const int h = ((int)i & 2047) >> 7;
    const float inv = 1.0f / (z_ws[h*TSEQ + t] + 1e-5f);
    const float4 a = *(const float4*)(O_ws + i);
    const float4 b = *(const float4*)(O_ws + i + 4);
    v8bf o;
    o[0] = (bf16)(a.x*inv); o[1] = (bf16)(a.y*inv); o[2] = (bf16)(a.z*inv); o[3] = (bf16)(a.w*inv);
    o[4] = (bf16)(b.x*inv); o[5] = (bf16)(b.y*inv); o[6] = (bf16)(b.z*inv); o[7] = (bf16)(b.w*inv);
    *(v8bf*)(ob + i) = o;
}

extern "C" void kernel_launch(void* const* d_in, const int* in_sizes, int n_in,
                              void* d_out, int out_size, void* d_ws, size_t ws_size,
                              hipStream_t stream)
{
    const float* hs    = (const float*)d_in[0];
    const float* Wq    = (const float*)d_in[1];
    const float* Wk    = (const float*)d_in[2];
    const float* Wv    = (const float*)d_in[3];
    const float* Wo    = (const float*)d_in[4];
    const float* gamma = (const float*)d_in[5];
    const float* beta  = (const float*)d_in[6];
    float* outp = (float*)d_out;

    const size_t MAT = (size_t)TSEQ * HIDDIM;     // 4.19M elems

    // bf16 ws slots (8.39 MB each); Wq_b/Wk_b live in d_out (16.78 MB), dead
    // after gemm_qkv; then d_out becomes the fp32 attention accumulator, then
    // the final output. vt aliases hs_b; ob aliases vb.
    bf16* ws   = (bf16*)d_ws;
    bf16* hs_b = ws + 0*MAT;
    bf16* vt   = hs_b;                            // alias: hs_b dead after gemm_qkv
    bf16* Wv_b = ws + 1*MAT;
    bf16* Wo_b = ws + 2*MAT;
    bf16* qb   = ws + 3*MAT;
    bf16* kb   = ws + 4*MAT;
    bf16* vb   = ws + 5*MAT;
    bf16* ob   = vb;                              // alias: vb dead after transpose
    float* z_ws = (float*)(ws + 6*MAT);           // [NHEAD][TSEQ] fp32, 131 KB
    bf16* Wq_b = (bf16*)d_out;
    bf16* Wk_b = (bf16*)d_out + MAT;
    float* O_ws = (float*)d_out;                  // fp32 accumulator, zeroed below

    conv5<<<dim3(2048, 5), 256, 0, stream>>>(hs, hs_b, Wq, Wq_b, Wk, Wk_b, Wv, Wv_b, Wo, Wo_b);
    gemm_qkv<<<dim3(48, 16), 256, 0, stream>>>(hs_b, Wq_b, Wk_b, Wv_b, qb, kb, vb);
    fmap<<<dim3(2*TSEQ*NHEAD/4), 256, 0, stream>>>(qb, kb, gamma, beta);
    transpose2048<<<dim3(32, 32), 256, 0, stream>>>(vb, vt);
    hipMemsetAsync(d_out, 0, MAT*sizeof(float), stream);        // O_ws = 0
    hipMemsetAsync(z_ws, 0, (size_t)TSEQ*NHEAD*sizeof(float), stream);
    attn<<<dim3(51, 16), 256, 0, stream>>>(qb, kb, vt, O_ws, z_ws);
    norm_div<<<dim3(MAT/8/256), 256, 0, stream>>>(O_ws, z_ws, ob);
    hipMemsetAsync(d_out, 0, MAT*sizeof(float), stream);        // reuse as gemm acc
    gemm_out_sk<<<dim3(16, 16, 2), 256, 0, stream>>>(ob, Wo_b, outp);
}

// Round 4
// 311.064 us; speedup vs baseline: 1.0646x; 1.0646x over previous
//
#include <hip/hip_runtime.h>
#include <hip/hip_bf16.h>
#include <stdint.h>

typedef __bf16 bf16;
typedef __bf16 v8bf __attribute__((ext_vector_type(8)));
typedef float  v4f  __attribute__((ext_vector_type(4)));

#define TSEQ   2048
#define HIDDIM 2048
#define NHEAD  16
#define HDIM   128

// async global->LDS, 16B per lane, LDS dest = wave-uniform base + lane*16 (m97 pattern)
__device__ __forceinline__ void async16(void* lds, const void* g)
{
    __builtin_amdgcn_global_load_lds(
        (__attribute__((address_space(1))) void*)(uintptr_t)g,
        (__attribute__((address_space(3))) void*)(unsigned int)(uintptr_t)lds,
        16, 0, 0);
}

// ---------------- f32 -> bf16 bulk convert: 5 matrices of TSEQ*HIDDIM ----------------
__global__ __launch_bounds__(256) void conv5(const float* __restrict__ s0, bf16* __restrict__ d0,
                                             const float* __restrict__ s1, bf16* __restrict__ d1,
                                             const float* __restrict__ s2, bf16* __restrict__ d2,
                                             const float* __restrict__ s3, bf16* __restrict__ d3,
                                             const float* __restrict__ s4, bf16* __restrict__ d4)
{
    const float* src; bf16* dst;
    switch (blockIdx.y) {
        case 0: src = s0; dst = d0; break;
        case 1: src = s1; dst = d1; break;
        case 2: src = s2; dst = d2; break;
        case 3: src = s3; dst = d3; break;
        default: src = s4; dst = d4; break;
    }
    const size_t i = ((size_t)blockIdx.x * 256 + threadIdx.x) * 8;
    const float4 a = *(const float4*)(src + i);
    const float4 b = *(const float4*)(src + i + 4);
    v8bf o;
    o[0] = (bf16)a.x; o[1] = (bf16)a.y; o[2] = (bf16)a.z; o[3] = (bf16)a.w;
    o[4] = (bf16)b.x; o[5] = (bf16)b.y; o[6] = (bf16)b.z; o[7] = (bf16)b.w;
    *(v8bf*)(dst + i) = o;
}

// ------- NT GEMM body: C[M,N] = A[M,K] * B[N,K]^T, 128x128 tile, BK=32 -------
template <typename CT>
__device__ __forceinline__ void gemm_body(const bf16* __restrict__ A,
                                          const bf16* __restrict__ B,
                                          CT* __restrict__ C,
                                          int m0, int n0, int K, int ldc)
{
    __shared__ __attribute__((aligned(16))) bf16 sA[128*32];
    __shared__ __attribute__((aligned(16))) bf16 sB[128*32];
    const int tid  = threadIdx.x;
    const int lane = tid & 63;
    const int w    = tid >> 6;           // wave 0..3
    const int wm   = w >> 1, wn = w & 1; // 2x2 waves of 64x64
    const int quad = lane >> 4, lr = lane & 15;
    const int srow = lane >> 2;          // staging: 16 rows x 4 lanes/row
    const int scol = (lane & 3) * 8;

    const bf16* gA0 = A + (size_t)(m0 + w*32 + srow) * K + scol;
    const bf16* gB0 = B + (size_t)(n0 + w*32 + srow) * K + scol;
    bf16* lA0 = &sA[w*1024];
    bf16* lB0 = &sB[w*1024];

    v4f acc[4][4] = {};

    for (int kt = 0; kt < K; kt += 32) {
        __syncthreads();                         // prev-iter LDS reads done
        async16(lA0,       gA0 + kt);
        async16(lA0 + 512, gA0 + (size_t)16*K + kt);
        async16(lB0,       gB0 + kt);
        async16(lB0 + 512, gB0 + (size_t)16*K + kt);
        __syncthreads();                         // drains vmcnt -> tiles visible
        v8bf a[4], b[4];
#pragma unroll
        for (int i = 0; i < 4; ++i)
            a[i] = *(const v8bf*)&sA[(wm*64 + i*16 + lr)*32 + quad*8];
#pragma unroll
        for (int j = 0; j < 4; ++j)
            b[j] = *(const v8bf*)&sB[(wn*64 + j*16 + lr)*32 + quad*8];
#pragma unroll
        for (int i = 0; i < 4; ++i)
#pragma unroll
            for (int j = 0; j < 4; ++j)
                acc[i][j] = __builtin_amdgcn_mfma_f32_16x16x32_bf16(a[i], b[j], acc[i][j], 0, 0, 0);
    }

#pragma unroll
    for (int i = 0; i < 4; ++i) {
        const int row_b = m0 + wm*64 + i*16 + quad*4;
#pragma unroll
        for (int j = 0; j < 4; ++j) {
            const int col = n0 + wn*64 + j*16 + lr;
#pragma unroll
            for (int r = 0; r < 4; ++r)
                C[(size_t)(row_b + r)*ldc + col] = (CT)acc[i][j][r];
        }
    }
}

__global__ __launch_bounds__(256) void gemm_qkv(const bf16* __restrict__ A,
    const bf16* __restrict__ Wq, const bf16* __restrict__ Wk, const bf16* __restrict__ Wv,
    bf16* __restrict__ qb, bf16* __restrict__ kb, bf16* __restrict__ vb)
{
    const int which = blockIdx.x >> 4;                   // 0:q 1:k 2:v
    const int n0 = (blockIdx.x & 15) * 128;
    const int m0 = blockIdx.y * 128;
    const bf16* B = (which == 0) ? Wq : (which == 1) ? Wk : Wv;
    bf16* C = (which == 0) ? qb : (which == 1) ? kb : vb;
    gemm_body<bf16>(A, B, C, m0, n0, HIDDIM, HIDDIM);
}

__global__ __launch_bounds__(256) void gemm_out(const bf16* __restrict__ A,
    const bf16* __restrict__ B, float* __restrict__ C)
{
    gemm_body<float>(A, B, C, blockIdx.y*128, blockIdx.x*128, HIDDIM, HIDDIM);
}

// ---------------- ReBased feature map: y = LN(x*gamma+beta), q also * D^-0.5 ----------------
__global__ __launch_bounds__(256) void fmap(bf16* __restrict__ qb, bf16* __restrict__ kb,
                                            const float* __restrict__ gamma,
                                            const float* __restrict__ beta)
{
    const int rid  = blockIdx.x * 4 + (threadIdx.x >> 6);   // 0 .. 2*T*H-1
    const int lane = threadIdx.x & 63;
    bf16* base = (rid < TSEQ*NHEAD) ? (qb + (size_t)rid * HDIM)
                                    : (kb + (size_t)(rid - TSEQ*NHEAD) * HDIM);
    const float scale = (rid < TSEQ*NHEAD) ? 0.08838834764831845f : 1.0f; // D^-0.5 on q only

    const bf16 x0b = base[lane*2], x1b = base[lane*2+1];
    const float g0 = gamma[lane*2], g1 = gamma[lane*2+1];
    const float b0 = beta[lane*2],  b1 = beta[lane*2+1];
    float x0 = (float)x0b*g0 + b0;
    float x1 = (float)x1b*g1 + b1;
    float s  = x0 + x1;
    float sq = x0*x0 + x1*x1;
#pragma unroll
    for (int off = 1; off < 64; off <<= 1) { s += __shfl_xor(s, off); sq += __shfl_xor(sq, off); }
    const float mu   = s * (1.0f/128.0f);
    float var        = sq * (1.0f/128.0f) - mu*mu;
    var = fmaxf(var, 0.0f);
    const float rstd = rsqrtf(var + 1e-5f);
    base[lane*2]   = (bf16)((x0 - mu) * rstd * scale);
    base[lane*2+1] = (bf16)((x1 - mu) * rstd * scale);
}

// ---------------- 2048x2048 transpose (vt[c][t] = vb[t][c]) ----------------
__global__ __launch_bounds__(256) void transpose2048(const bf16* __restrict__ src,
                                                     bf16* __restrict__ dst)
{
    __shared__ __attribute__((aligned(16))) bf16 tile[64][72];
    const int t0 = blockIdx.y * 64, c0 = blockIdx.x * 64;
    const int tid = threadIdx.x;
    const int r = tid >> 3;            // 0..31
    const int c = (tid & 7) * 8;       // 0..56
#pragma unroll
    for (int p = 0; p < 2; ++p) {
        const int rr = r + p*32;
        *(v8bf*)&tile[rr][c] = *(const v8bf*)(src + (size_t)(t0+rr)*HIDDIM + c0 + c);
    }
    __syncthreads();
#pragma unroll
    for (int p = 0; p < 2; ++p) {
        const int orow = r + p*32;     // output row = original column
        v8bf o;
#pragma unroll
        for (int i = 0; i < 8; ++i) o[i] = tile[c + i][orow];
        *(v8bf*)(dst + (size_t)(c0+orow)*HIDDIM + t0 + c) = o;
    }
}

// ---------------- quadratic causal attention, 64-row q-tiles ----------------
// grid (32 tiles, 16 heads) = 512 blocks -> 2 blocks/CU (8 waves) for latency hiding.
// tile = 31-bx (big-first, greedy LPT balance). Full key range in-block:
// z finalizes locally, direct bf16 writes, NO atomics.
__global__ __launch_bounds__(256) void attn(const bf16* __restrict__ qb,
                                            const bf16* __restrict__ kb,
                                            const bf16* __restrict__ vt,
                                            bf16* __restrict__ ob)
{
    __shared__ __attribute__((aligned(16))) bf16 sK[64*136];   // [s][d], pad 8
    __shared__ __attribute__((aligned(16))) bf16 sV[128*72];   // [d][s], pad 8
    __shared__ __attribute__((aligned(16))) bf16 sS[64*72];    // [q][s], pad 8
    const int h    = blockIdx.y;
    const int tile = 31 - blockIdx.x;         // 64-row tile; big workloads first
    const int tid  = threadIdx.x, lane = tid & 63, w = tid >> 6;
    const int quad = lane >> 4, lr = lane & 15;

    // Q fragments (A-layout): wave w owns rows [tile*64 + w*16, +16)
    v8bf qa[4];
    {
        const bf16* q0 = qb + (size_t)(tile*64 + w*16 + lr)*HIDDIM + h*HDIM + quad*8;
#pragma unroll
        for (int ks = 0; ks < 4; ++ks)
            qa[ks] = *(const v8bf*)(q0 + ks*32);
    }

    v4f  o[8] = {};
    float z[4] = {};
    const int nch = tile + 1;

    for (int ch = 0; ch < nch; ++ch) {
        const int s0 = ch * 64;
        const bool diag = (ch == tile);
        __syncthreads();                        // prev-chunk LDS reads done
        {   // stage K tile [64 s][128 d]
            const int r  = tid >> 4;            // 0..15
            const int c  = (tid & 15) * 8;
#pragma unroll
            for (int p = 0; p < 4; ++p) {
                const int rr = r + p*16;
                *(v8bf*)&sK[rr*136 + c] =
                    *(const v8bf*)(kb + (size_t)(s0+rr)*HIDDIM + h*HDIM + c);
            }
            // stage Vt tile [128 d][64 s]
            const int r2 = tid >> 3;            // 0..31
            const int c2 = (tid & 7) * 8;
#pragma unroll
            for (int p = 0; p < 4; ++p) {
                const int rr = r2 + p*32;
                *(v8bf*)&sV[rr*72 + c2] =
                    *(const v8bf*)(vt + (size_t)(h*HDIM+rr)*HIDDIM + s0 + c2);
            }
        }
        __syncthreads();                        // tiles visible

        // QK^T -> square/mask -> z, sS (sS rows are wave-private: no barrier needed)
        v8bf kbf[4][4];
#pragma unroll
        for (int nj = 0; nj < 4; ++nj)
#pragma unroll
            for (int ks = 0; ks < 4; ++ks)
                kbf[nj][ks] = *(const v8bf*)&sK[(nj*16 + lr)*136 + ks*32 + quad*8];
        const int row_l = w*16 + quad*4;
        const int qg    = tile*64 + row_l;
#pragma unroll
        for (int nj = 0; nj < 4; ++nj) {
            v4f s4 = {0.f, 0.f, 0.f, 0.f};
#pragma unroll
            for (int ks = 0; ks < 4; ++ks)
                s4 = __builtin_amdgcn_mfma_f32_16x16x32_bf16(qa[ks], kbf[nj][ks], s4, 0, 0, 0);
            const int col = nj*16 + lr;
            const int sg  = s0 + col;
#pragma unroll
            for (int r = 0; r < 4; ++r) {
                float val = s4[r] * s4[r];
                if (diag && (sg > qg + r)) val = 0.0f;
                const bf16 vb16 = (bf16)val;
                z[r] += (float)vb16;            // consistent with what multiplies V
                sS[(row_l + r)*72 + col] = vb16;
            }
        }

        // O += S * V
#pragma unroll
        for (int ks = 0; ks < 2; ++ks) {
            const v8bf sa = *(const v8bf*)&sS[(w*16 + lr)*72 + ks*32 + quad*8];
#pragma unroll
            for (int nd = 0; nd < 8; ++nd) {
                const v8bf vbf = *(const v8bf*)&sV[(nd*16 + lr)*72 + ks*32 + quad*8];
                o[nd] = __builtin_amdgcn_mfma_f32_16x16x32_bf16(sa, vbf, o[nd], 0, 0, 0);
            }
        }
    }

    // z: sum across the 16-lane group (each lane accumulated 4 of every 64 cols)
#pragma unroll
    for (int r = 0; r < 4; ++r) {
        float zz = z[r];
        zz += __shfl_xor(zz, 1); zz += __shfl_xor(zz, 2);
        zz += __shfl_xor(zz, 4); zz += __shfl_xor(zz, 8);
        z[r] = zz + 1e-5f;
    }

    // epilogue: ob[t][h*128+d] = O / (z + eps)
    {
        const int row_l = w*16 + quad*4;
        const size_t rbase = (size_t)(tile*64 + row_l)*HIDDIM + h*HDIM;
#pragma unroll
        for (int nd = 0; nd < 8; ++nd) {
            const int col = nd*16 + lr;
#pragma unroll
            for (int r = 0; r < 4; ++r)
                ob[rbase + (size_t)r*HIDDIM + col] = (bf16)(o[nd][r] / z[r]);
        }
    }
}

extern "C" void kernel_launch(void* const* d_in, const int* in_sizes, int n_in,
                              void* d_out, int out_size, void* d_ws, size_t ws_size,
                              hipStream_t stream)
{
    const float* hs    = (const float*)d_in[0];
    const float* Wq    = (const float*)d_in[1];
    const float* Wk    = (const float*)d_in[2];
    const float* Wv    = (const float*)d_in[3];
    const float* Wo    = (const float*)d_in[4];
    const float* gamma = (const float*)d_in[5];
    const float* beta  = (const float*)d_in[6];
    float* outp = (float*)d_out;

    const size_t MAT = (size_t)TSEQ * HIDDIM;     // 4.19M elems

    // bf16 ws slots (8.39 MB each); Wq_b/Wk_b live in d_out (16.78 MB), dead
    // after gemm_qkv; d_out then becomes the final output. vt aliases hs_b;
    // ob aliases vb.
    bf16* ws   = (bf16*)d_ws;
    bf16* hs_b = ws + 0*MAT;
    bf16* vt   = hs_b;                            // alias: hs_b dead after gemm_qkv
    bf16* Wv_b = ws + 1*MAT;
    bf16* Wo_b = ws + 2*MAT;
    bf16* qb   = ws + 3*MAT;
    bf16* kb   = ws + 4*MAT;
    bf16* vb   = ws + 5*MAT;
    bf16* ob   = vb;                              // alias: vb dead after transpose
    bf16* Wq_b = (bf16*)d_out;
    bf16* Wk_b = (bf16*)d_out + MAT;

    conv5<<<dim3(2048, 5), 256, 0, stream>>>(hs, hs_b, Wq, Wq_b, Wk, Wk_b, Wv, Wv_b, Wo, Wo_b);
    gemm_qkv<<<dim3(48, 16), 256, 0, stream>>>(hs_b, Wq_b, Wk_b, Wv_b, qb, kb, vb);
    fmap<<<dim3(2*TSEQ*NHEAD/4), 256, 0, stream>>>(qb, kb, gamma, beta);
    transpose2048<<<dim3(32, 32), 256, 0, stream>>>(vb, vt);
    attn<<<dim3(32, 16), 256, 0, stream>>>(qb, kb, vt, ob);
    gemm_out<<<dim3(16, 16), 256, 0, stream>>>(ob, Wo_b, outp);
}

// Round 5
// 301.401 us; speedup vs baseline: 1.0987x; 1.0321x over previous
//
#include <hip/hip_runtime.h>
#include <hip/hip_bf16.h>
#include <stdint.h>

typedef __bf16 bf16;
typedef __bf16 v8bf __attribute__((ext_vector_type(8)));
typedef float  v4f  __attribute__((ext_vector_type(4)));

#define TSEQ   2048
#define HIDDIM 2048
#define NHEAD  16
#define HDIM   128

// async global->LDS, 16B per lane, LDS dest = wave-uniform base + lane*16 (m97 pattern)
__device__ __forceinline__ void async16(void* lds, const void* g)
{
    __builtin_amdgcn_global_load_lds(
        (__attribute__((address_space(1))) void*)(uintptr_t)g,
        (__attribute__((address_space(3))) void*)(unsigned int)(uintptr_t)lds,
        16, 0, 0);
}

// ---------------- f32 -> bf16 bulk convert: 5 matrices of TSEQ*HIDDIM ----------------
__global__ __launch_bounds__(256) void conv5(const float* __restrict__ s0, bf16* __restrict__ d0,
                                             const float* __restrict__ s1, bf16* __restrict__ d1,
                                             const float* __restrict__ s2, bf16* __restrict__ d2,
                                             const float* __restrict__ s3, bf16* __restrict__ d3,
                                             const float* __restrict__ s4, bf16* __restrict__ d4)
{
    const float* src; bf16* dst;
    switch (blockIdx.y) {
        case 0: src = s0; dst = d0; break;
        case 1: src = s1; dst = d1; break;
        case 2: src = s2; dst = d2; break;
        case 3: src = s3; dst = d3; break;
        default: src = s4; dst = d4; break;
    }
    const size_t i = ((size_t)blockIdx.x * 256 + threadIdx.x) * 8;
    const float4 a = *(const float4*)(src + i);
    const float4 b = *(const float4*)(src + i + 4);
    v8bf o;
    o[0] = (bf16)a.x; o[1] = (bf16)a.y; o[2] = (bf16)a.z; o[3] = (bf16)a.w;
    o[4] = (bf16)b.x; o[5] = (bf16)b.y; o[6] = (bf16)b.z; o[7] = (bf16)b.w;
    *(v8bf*)(dst + i) = o;
}

// ------- NT GEMM body: C[M,N] = A[M,K] * B[N,K]^T, 128x128 tile, BK=32 -------
template <typename CT>
__device__ __forceinline__ void gemm_body(const bf16* __restrict__ A,
                                          const bf16* __restrict__ B,
                                          CT* __restrict__ C,
                                          int m0, int n0, int K, int ldc)
{
    __shared__ __attribute__((aligned(16))) bf16 sA[128*32];
    __shared__ __attribute__((aligned(16))) bf16 sB[128*32];
    const int tid  = threadIdx.x;
    const int lane = tid & 63;
    const int w    = tid >> 6;           // wave 0..3
    const int wm   = w >> 1, wn = w & 1; // 2x2 waves of 64x64
    const int quad = lane >> 4, lr = lane & 15;
    const int srow = lane >> 2;          // staging: 16 rows x 4 lanes/row
    const int scol = (lane & 3) * 8;

    const bf16* gA0 = A + (size_t)(m0 + w*32 + srow) * K + scol;
    const bf16* gB0 = B + (size_t)(n0 + w*32 + srow) * K + scol;
    bf16* lA0 = &sA[w*1024];
    bf16* lB0 = &sB[w*1024];

    v4f acc[4][4] = {};

    for (int kt = 0; kt < K; kt += 32) {
        __syncthreads();                         // prev-iter LDS reads done
        async16(lA0,       gA0 + kt);
        async16(lA0 + 512, gA0 + (size_t)16*K + kt);
        async16(lB0,       gB0 + kt);
        async16(lB0 + 512, gB0 + (size_t)16*K + kt);
        __syncthreads();                         // drains vmcnt -> tiles visible
        v8bf a[4], b[4];
#pragma unroll
        for (int i = 0; i < 4; ++i)
            a[i] = *(const v8bf*)&sA[(wm*64 + i*16 + lr)*32 + quad*8];
#pragma unroll
        for (int j = 0; j < 4; ++j)
            b[j] = *(const v8bf*)&sB[(wn*64 + j*16 + lr)*32 + quad*8];
#pragma unroll
        for (int i = 0; i < 4; ++i)
#pragma unroll
            for (int j = 0; j < 4; ++j)
                acc[i][j] = __builtin_amdgcn_mfma_f32_16x16x32_bf16(a[i], b[j], acc[i][j], 0, 0, 0);
    }

#pragma unroll
    for (int i = 0; i < 4; ++i) {
        const int row_b = m0 + wm*64 + i*16 + quad*4;
#pragma unroll
        for (int j = 0; j < 4; ++j) {
            const int col = n0 + wn*64 + j*16 + lr;
#pragma unroll
            for (int r = 0; r < 4; ++r)
                C[(size_t)(row_b + r)*ldc + col] = (CT)acc[i][j][r];
        }
    }
}

__global__ __launch_bounds__(256) void gemm_qkv(const bf16* __restrict__ A,
    const bf16* __restrict__ Wq, const bf16* __restrict__ Wk, const bf16* __restrict__ Wv,
    bf16* __restrict__ qb, bf16* __restrict__ kb, bf16* __restrict__ vb)
{
    const int which = blockIdx.x >> 4;                   // 0:q 1:k 2:v
    const int n0 = (blockIdx.x & 15) * 128;
    const int m0 = blockIdx.y * 128;
    const bf16* B = (which == 0) ? Wq : (which == 1) ? Wk : Wv;
    bf16* C = (which == 0) ? qb : (which == 1) ? kb : vb;
    gemm_body<bf16>(A, B, C, m0, n0, HIDDIM, HIDDIM);
}

// ------- 128x64-tile NT GEMM (fp32 out): 512 blocks -> 2 blocks/CU for overlap -------
__global__ __launch_bounds__(256) void gemm_out(const bf16* __restrict__ A,
    const bf16* __restrict__ B, float* __restrict__ C)
{
    __shared__ __attribute__((aligned(16))) bf16 sA[128*32];
    __shared__ __attribute__((aligned(16))) bf16 sB[64*32];
    const int m0 = blockIdx.y * 128, n0 = blockIdx.x * 64;
    const int K = HIDDIM, ldc = HIDDIM;
    const int tid  = threadIdx.x;
    const int lane = tid & 63;
    const int w    = tid >> 6;           // wave 0..3
    const int wm   = w >> 1, wn = w & 1; // 2x2 waves of 64x32
    const int quad = lane >> 4, lr = lane & 15;
    const int srow = lane >> 2;          // staging: 16 rows x 4 lanes/row
    const int scol = (lane & 3) * 8;

    const bf16* gA0 = A + (size_t)(m0 + w*32 + srow) * K + scol;
    const bf16* gB0 = B + (size_t)(n0 + w*16 + srow) * K + scol;
    bf16* lA0 = &sA[w*1024];
    bf16* lB0 = &sB[w*512];

    v4f acc[4][2] = {};

    for (int kt = 0; kt < K; kt += 32) {
        __syncthreads();
        async16(lA0,       gA0 + kt);
        async16(lA0 + 512, gA0 + (size_t)16*K + kt);
        async16(lB0,       gB0 + kt);
        __syncthreads();
        v8bf a[4], b[2];
#pragma unroll
        for (int i = 0; i < 4; ++i)
            a[i] = *(const v8bf*)&sA[(wm*64 + i*16 + lr)*32 + quad*8];
#pragma unroll
        for (int j = 0; j < 2; ++j)
            b[j] = *(const v8bf*)&sB[(wn*32 + j*16 + lr)*32 + quad*8];
#pragma unroll
        for (int i = 0; i < 4; ++i)
#pragma unroll
            for (int j = 0; j < 2; ++j)
                acc[i][j] = __builtin_amdgcn_mfma_f32_16x16x32_bf16(a[i], b[j], acc[i][j], 0, 0, 0);
    }

#pragma unroll
    for (int i = 0; i < 4; ++i) {
        const int row_b = m0 + wm*64 + i*16 + quad*4;
#pragma unroll
        for (int j = 0; j < 2; ++j) {
            const int col = n0 + wn*32 + j*16 + lr;
#pragma unroll
            for (int r = 0; r < 4; ++r)
                C[(size_t)(row_b + r)*ldc + col] = acc[i][j][r];
        }
    }
}

// ---------------- ReBased feature map: y = LN(x*gamma+beta), q also * D^-0.5 ----------------
__global__ __launch_bounds__(256) void fmap(bf16* __restrict__ qb, bf16* __restrict__ kb,
                                            const float* __restrict__ gamma,
                                            const float* __restrict__ beta)
{
    const int rid  = blockIdx.x * 4 + (threadIdx.x >> 6);   // 0 .. 2*T*H-1
    const int lane = threadIdx.x & 63;
    bf16* base = (rid < TSEQ*NHEAD) ? (qb + (size_t)rid * HDIM)
                                    : (kb + (size_t)(rid - TSEQ*NHEAD) * HDIM);
    const float scale = (rid < TSEQ*NHEAD) ? 0.08838834764831845f : 1.0f; // D^-0.5 on q only

    const bf16 x0b = base[lane*2], x1b = base[lane*2+1];
    const float g0 = gamma[lane*2], g1 = gamma[lane*2+1];
    const float b0 = beta[lane*2],  b1 = beta[lane*2+1];
    float x0 = (float)x0b*g0 + b0;
    float x1 = (float)x1b*g1 + b1;
    float s  = x0 + x1;
    float sq = x0*x0 + x1*x1;
#pragma unroll
    for (int off = 1; off < 64; off <<= 1) { s += __shfl_xor(s, off); sq += __shfl_xor(sq, off); }
    const float mu   = s * (1.0f/128.0f);
    float var        = sq * (1.0f/128.0f) - mu*mu;
    var = fmaxf(var, 0.0f);
    const float rstd = rsqrtf(var + 1e-5f);
    base[lane*2]   = (bf16)((x0 - mu) * rstd * scale);
    base[lane*2+1] = (bf16)((x1 - mu) * rstd * scale);
}

// ---------------- 2048x2048 transpose (vt[c][t] = vb[t][c]) ----------------
__global__ __launch_bounds__(256) void transpose2048(const bf16* __restrict__ src,
                                                     bf16* __restrict__ dst)
{
    __shared__ __attribute__((aligned(16))) bf16 tile[64][72];
    const int t0 = blockIdx.y * 64, c0 = blockIdx.x * 64;
    const int tid = threadIdx.x;
    const int r = tid >> 3;            // 0..31
    const int c = (tid & 7) * 8;       // 0..56
#pragma unroll
    for (int p = 0; p < 2; ++p) {
        const int rr = r + p*32;
        *(v8bf*)&tile[rr][c] = *(const v8bf*)(src + (size_t)(t0+rr)*HIDDIM + c0 + c);
    }
    __syncthreads();
#pragma unroll
    for (int p = 0; p < 2; ++p) {
        const int orow = r + p*32;     // output row = original column
        v8bf o;
#pragma unroll
        for (int i = 0; i < 8; ++i) o[i] = tile[c + i][orow];
        *(v8bf*)(dst + (size_t)(c0+orow)*HIDDIM + t0 + c) = o;
    }
}

// ---------------- quadratic causal attention, 64-row q-tiles, pipelined ----------------
// grid (32 tiles, 16 heads) = 512 blocks -> 2 blocks/CU. tile = 31-bx (LPT).
// VGPR double-buffer: chunk ch+1's K/V global loads issue during chunk ch's compute,
// so the vmcnt wait lands ~1000 cyc after issue instead of immediately.
__global__ __launch_bounds__(256) void attn(const bf16* __restrict__ qb,
                                            const bf16* __restrict__ kb,
                                            const bf16* __restrict__ vt,
                                            bf16* __restrict__ ob)
{
    __shared__ __attribute__((aligned(16))) bf16 sK[64*136];   // [s][d], pad 8
    __shared__ __attribute__((aligned(16))) bf16 sV[128*72];   // [d][s], pad 8
    __shared__ __attribute__((aligned(16))) bf16 sS[64*72];    // [q][s], pad 8
    const int h    = blockIdx.y;
    const int tile = 31 - blockIdx.x;         // 64-row tile; big workloads first
    const int tid  = threadIdx.x, lane = tid & 63, w = tid >> 6;
    const int quad = lane >> 4, lr = lane & 15;

    // Q fragments (A-layout): wave w owns rows [tile*64 + w*16, +16)
    v8bf qa[4];
    {
        const bf16* q0 = qb + (size_t)(tile*64 + w*16 + lr)*HIDDIM + h*HDIM + quad*8;
#pragma unroll
        for (int ks = 0; ks < 4; ++ks)
            qa[ks] = *(const v8bf*)(q0 + ks*32);
    }

    // staging coordinates
    const int rK = tid >> 4, cK = (tid & 15) * 8;   // K: 16 rows x 16 lane-cols
    const int rV = tid >> 3, cV = (tid & 7) * 8;    // V: 32 rows x 8 lane-cols

    v8bf curK[4], curV[4], nxtK[4], nxtV[4];
#pragma unroll
    for (int p = 0; p < 4; ++p) {
        curK[p] = *(const v8bf*)(kb + (size_t)(rK + p*16)*HIDDIM + h*HDIM + cK);
        curV[p] = *(const v8bf*)(vt + (size_t)(h*HDIM + rV + p*32)*HIDDIM + cV);
    }

    v4f  o[8] = {};
    float z[4] = {};
    const int nch = tile + 1;

    for (int ch = 0; ch < nch; ++ch) {
        const int s0 = ch * 64;
        const bool diag = (ch == tile);
        __syncthreads();                        // prev-chunk LDS reads done
#pragma unroll
        for (int p = 0; p < 4; ++p)
            *(v8bf*)&sK[(rK + p*16)*136 + cK] = curK[p];
#pragma unroll
        for (int p = 0; p < 4; ++p)
            *(v8bf*)&sV[(rV + p*32)*72 + cV] = curV[p];
        if (ch + 1 < nch) {                     // prefetch next chunk (overlaps compute)
            const int s1 = s0 + 64;
#pragma unroll
            for (int p = 0; p < 4; ++p) {
                nxtK[p] = *(const v8bf*)(kb + (size_t)(s1 + rK + p*16)*HIDDIM + h*HDIM + cK);
                nxtV[p] = *(const v8bf*)(vt + (size_t)(h*HDIM + rV + p*32)*HIDDIM + s1 + cV);
            }
        }
        __syncthreads();                        // tiles visible

        // QK^T -> square/mask -> z, sS (sS rows are wave-private: no barrier needed)
        v8bf kbf[4][4];
#pragma unroll
        for (int nj = 0; nj < 4; ++nj)
#pragma unroll
            for (int ks = 0; ks < 4; ++ks)
                kbf[nj][ks] = *(const v8bf*)&sK[(nj*16 + lr)*136 + ks*32 + quad*8];
        const int row_l = w*16 + quad*4;
        const int qg    = tile*64 + row_l;
#pragma unroll
        for (int nj = 0; nj < 4; ++nj) {
            v4f s4 = {0.f, 0.f, 0.f, 0.f};
#pragma unroll
            for (int ks = 0; ks < 4; ++ks)
                s4 = __builtin_amdgcn_mfma_f32_16x16x32_bf16(qa[ks], kbf[nj][ks], s4, 0, 0, 0);
            const int col = nj*16 + lr;
            const int sg  = s0 + col;
#pragma unroll
            for (int r = 0; r < 4; ++r) {
                float val = s4[r] * s4[r];
                if (diag && (sg > qg + r)) val = 0.0f;
                const bf16 vb16 = (bf16)val;
                z[r] += (float)vb16;            // consistent with what multiplies V
                sS[(row_l + r)*72 + col] = vb16;
            }
        }

        // O += S * V
#pragma unroll
        for (int ks = 0; ks < 2; ++ks) {
            const v8bf sa = *(const v8bf*)&sS[(w*16 + lr)*72 + ks*32 + quad*8];
#pragma unroll
            for (int nd = 0; nd < 8; ++nd) {
                const v8bf vbf = *(const v8bf*)&sV[(nd*16 + lr)*72 + ks*32 + quad*8];
                o[nd] = __builtin_amdgcn_mfma_f32_16x16x32_bf16(sa, vbf, o[nd], 0, 0, 0);
            }
        }

        if (ch + 1 < nch) {                     // rotate buffers (vmcnt waits here, late)
#pragma unroll
            for (int p = 0; p < 4; ++p) { curK[p] = nxtK[p]; curV[p] = nxtV[p]; }
        }
    }

    // z: sum across the 16-lane group (each lane accumulated 4 of every 64 cols)
#pragma unroll
    for (int r = 0; r < 4; ++r) {
        float zz = z[r];
        zz += __shfl_xor(zz, 1); zz += __shfl_xor(zz, 2);
        zz += __shfl_xor(zz, 4); zz += __shfl_xor(zz, 8);
        z[r] = zz + 1e-5f;
    }

    // epilogue: ob[t][h*128+d] = O / (z + eps)
    {
        const int row_l = w*16 + quad*4;
        const size_t rbase = (size_t)(tile*64 + row_l)*HIDDIM + h*HDIM;
#pragma unroll
        for (int nd = 0; nd < 8; ++nd) {
            const int col = nd*16 + lr;
#pragma unroll
            for (int r = 0; r < 4; ++r)
                ob[rbase + (size_t)r*HIDDIM + col] = (bf16)(o[nd][r] / z[r]);
        }
    }
}

extern "C" void kernel_launch(void* const* d_in, const int* in_sizes, int n_in,
                              void* d_out, int out_size, void* d_ws, size_t ws_size,
                              hipStream_t stream)
{
    const float* hs    = (const float*)d_in[0];
    const float* Wq    = (const float*)d_in[1];
    const float* Wk    = (const float*)d_in[2];
    const float* Wv    = (const float*)d_in[3];
    const float* Wo    = (const float*)d_in[4];
    const float* gamma = (const float*)d_in[5];
    const float* beta  = (const float*)d_in[6];
    float* outp = (float*)d_out;

    const size_t MAT = (size_t)TSEQ * HIDDIM;     // 4.19M elems

    // bf16 ws slots (8.39 MB each); Wq_b/Wk_b live in d_out (16.78 MB), dead
    // after gemm_qkv; d_out then becomes the final output. vt aliases hs_b;
    // ob aliases vb.
    bf16* ws   = (bf16*)d_ws;
    bf16* hs_b = ws + 0*MAT;
    bf16* vt   = hs_b;                            // alias: hs_b dead after gemm_qkv
    bf16* Wv_b = ws + 1*MAT;
    bf16* Wo_b = ws + 2*MAT;
    bf16* qb   = ws + 3*MAT;
    bf16* kb   = ws + 4*MAT;
    bf16* vb   = ws + 5*MAT;
    bf16* ob   = vb;                              // alias: vb dead after transpose
    bf16* Wq_b = (bf16*)d_out;
    bf16* Wk_b = (bf16*)d_out + MAT;

    conv5<<<dim3(2048, 5), 256, 0, stream>>>(hs, hs_b, Wq, Wq_b, Wk, Wk_b, Wv, Wv_b, Wo, Wo_b);
    gemm_qkv<<<dim3(48, 16), 256, 0, stream>>>(hs_b, Wq_b, Wk_b, Wv_b, qb, kb, vb);
    fmap<<<dim3(2*TSEQ*NHEAD/4), 256, 0, stream>>>(qb, kb, gamma, beta);
    transpose2048<<<dim3(32, 32), 256, 0, stream>>>(vb, vt);
    attn<<<dim3(32, 16), 256, 0, stream>>>(qb, kb, vt, ob);
    gemm_out<<<dim3(32, 16), 256, 0, stream>>>(ob, Wo_b, outp);
}